// Round 3
// baseline (7173.810 us; speedup 1.0000x reference)
//
#include <hip/hip_runtime.h>
#include <hip/hip_bf16.h>
#include <cstdint>

// ---------------------------------------------------------------------------
// BiLSTM: x[2048,1024] -> bidirectional LSTM (H=1024) -> FC to 1000 classes.
//   1. convert_all: fp32 -> f16 copies of x, W_ih_f, W_ih_b, fc_W
//   2. gemm_f16<0>: x_proj_d = x_d @ W_ih_d^T + b_ih + b_hh   (f16 MFMA)
//   3. lstm_rec R8: back to the PROVEN R5 agent-scope handshake (the L2
//      fast-path gamble is dead: R6+R7 falsified sc0-visibility twice).
//      Kept from R7 (verified correct+cheap): gates-per-lane layout (lane =
//      [rr|kq], 4 accs = 4 gates of one unit -> no redistribution), 16-lane
//      DPP VALU reduce (replaces 16 LDS-pipe shuffles + LDS transpose),
//      2-shuffle publish. NEW: depth-2 pipelined polling — two poll batches
//      in flight; check A while B is in flight, reissue A before checking B.
//      Poll period L -> ~L/2, detection ~arrival+L instead of ~arrival+1.5L,
//      and it shrinks the barrier's max-over-256-threads tail.
//   4. gemm_f16<1>: out = h_hist @ fc_W^T + fc_b
// ---------------------------------------------------------------------------

typedef __fp16 h2 __attribute__((ext_vector_type(2)));
typedef __fp16 h8 __attribute__((ext_vector_type(8)));
typedef float f4 __attribute__((ext_vector_type(4)));
typedef unsigned long long u64;

#define T_LEN 2048

static __device__ __forceinline__ unsigned int packh2(float a, float b) {
  h2 r = __builtin_amdgcn_cvt_pkrtz(a, b);
  return __builtin_bit_cast(unsigned int, r);
}
static __device__ __forceinline__ float fdot2u(unsigned int a, unsigned int b, float c) {
  return __builtin_amdgcn_fdot2(__builtin_bit_cast(h2, a), __builtin_bit_cast(h2, b), c, false);
}
static __device__ __forceinline__ float sigmoidf_(float x) {
  return 1.f / (1.f + __expf(-x));
}
static __device__ __forceinline__ float tanhf_(float x) {
  float e = __expf(-2.f * fabsf(x));
  float r = (1.f - e) / (1.f + e);
  return copysignf(r, x);
}
static __device__ __forceinline__ u64 aload(const u64* p) {
  return __hip_atomic_load(p, __ATOMIC_RELAXED, __HIP_MEMORY_SCOPE_AGENT);
}

// 16-lane (DPP-row) sum reduction: xor1, xor2 (quad_perm), row_half_mirror,
// row_mirror. All 16 lanes of the row end with the row sum. (R7-verified.)
#define DPP_ADD1(v, CTRL)                                                      \
  v += __builtin_bit_cast(                                                     \
      float, __builtin_amdgcn_update_dpp(0, __builtin_bit_cast(int, v), CTRL,  \
                                         0xf, 0xf, true))
#define DPP_ROUND(CTRL)                                                        \
  DPP_ADD1(acc0, CTRL);                                                        \
  DPP_ADD1(acc1, CTRL);                                                        \
  DPP_ADD1(acc2, CTRL);                                                        \
  DPP_ADD1(acc3, CTRL)

// ---------------------------------------------------------------------------
__global__ void convert_all(const float* __restrict__ x, const float* __restrict__ wf,
                            const float* __restrict__ wb, const float* __restrict__ fcw,
                            _Float16* __restrict__ xf, _Float16* __restrict__ wff,
                            _Float16* __restrict__ wbf, _Float16* __restrict__ fcwf) {
  const size_t SX = 2097152, SW = 4194304, SFC = 2097152;
  size_t i = (size_t)blockIdx.x * 256 + threadIdx.x;
  if (i < SX) {
    xf[i] = (_Float16)x[i];
  } else if (i < SX + SW) {
    size_t j = i - SX; wff[j] = (_Float16)wf[j];
  } else if (i < SX + 2 * SW) {
    size_t j = i - SX - SW; wbf[j] = (_Float16)wb[j];
  } else if (i < SX + 2 * SW + SFC) {
    size_t j = i - SX - 2 * SW;
    int row = (int)(j >> 11), col = (int)(j & 2047);
    fcwf[j] = (row < 1000) ? (_Float16)fcw[(size_t)row * 2048 + col] : (_Float16)0.f;
  }
}

// epoch bump + seed gen-0 tags (payload h=0, tag=epoch<<12).
__global__ void init_state(u64* __restrict__ hc, unsigned* __restrict__ ep) {
  __shared__ unsigned sbs;
  if (threadIdx.x == 0) sbs = atomicAdd(ep, 1u) << 12;
  __syncthreads();
  u64 v = (u64)sbs;
  for (int i = threadIdx.x; i < 2048; i += 256)
    __hip_atomic_store(&hc[i], v, __ATOMIC_RELAXED, __HIP_MEMORY_SCOPE_AGENT);
}

// ---------------------------------------------------------------------------
// f16 GEMM, 128x128 tile, BK=64 (unchanged — verified R2/R3/R4)
// ---------------------------------------------------------------------------
#define LSTR 80

template <int MODE>
__global__ __launch_bounds__(256, 2) void gemm_f16(
    const _Float16* __restrict__ A, const _Float16* __restrict__ B,
    const float* __restrict__ bias1, const float* __restrict__ bias2,
    void* __restrict__ Cout, int M, int N, int K, int nout, int rev) {
  __shared__ _Float16 As[128 * LSTR];
  __shared__ _Float16 Bs[128 * LSTR];

  const int tid = threadIdx.x;
  const int ntn = N >> 7;
  const int tm = blockIdx.x / ntn, tn = blockIdx.x % ntn;
  const int wid = tid >> 6, lane = tid & 63;
  const int wr = wid >> 1, wc = wid & 1;
  const int quad = lane >> 4, l16 = lane & 15;

  const int srow = tid >> 1, seg = tid & 1;
  const int arow = rev ? (M - 1 - (tm * 128 + srow)) : (tm * 128 + srow);
  const int brow = tn * 128 + srow;

  f4 acc[4][4];
#pragma unroll
  for (int i = 0; i < 4; ++i)
#pragma unroll
    for (int j = 0; j < 4; ++j) acc[i][j] = (f4)0.f;

  for (int k0 = 0; k0 < K; k0 += 64) {
    uint4 va[4], vb[4];
    const uint4* gpa = (const uint4*)(A + (size_t)arow * K + k0 + seg * 32);
    const uint4* gpb = (const uint4*)(B + (size_t)brow * K + k0 + seg * 32);
#pragma unroll
    for (int c = 0; c < 4; ++c) va[c] = gpa[c];
#pragma unroll
    for (int c = 0; c < 4; ++c) vb[c] = gpb[c];

    __syncthreads();
    uint4* lpa = (uint4*)&As[srow * LSTR + seg * 32];
    uint4* lpb = (uint4*)&Bs[srow * LSTR + seg * 32];
#pragma unroll
    for (int c = 0; c < 4; ++c) lpa[c] = va[c];
#pragma unroll
    for (int c = 0; c < 4; ++c) lpb[c] = vb[c];
    __syncthreads();

#pragma unroll
    for (int kk = 0; kk < 64; kk += 32) {
      h8 af[4], bf[4];
#pragma unroll
      for (int i = 0; i < 4; ++i) {
        int m = wr * 64 + i * 16 + l16;
        af[i] = *(const h8*)&As[m * LSTR + kk + quad * 8];
        int n = wc * 64 + i * 16 + l16;
        bf[i] = *(const h8*)&Bs[n * LSTR + kk + quad * 8];
      }
#pragma unroll
      for (int i = 0; i < 4; ++i)
#pragma unroll
        for (int j = 0; j < 4; ++j)
          acc[i][j] = __builtin_amdgcn_mfma_f32_16x16x32_f16(af[i], bf[j], acc[i][j], 0, 0, 0);
    }
  }

  const int cm0 = tm * 128 + wr * 64, cn0 = tn * 128 + wc * 64;
#pragma unroll
  for (int i = 0; i < 4; ++i) {
#pragma unroll
    for (int j = 0; j < 4; ++j) {
      int n = cn0 + j * 16 + l16;
#pragma unroll
      for (int r = 0; r < 4; ++r) {
        int m = cm0 + i * 16 + quad * 4 + r;
        float v = acc[i][j][r];
        if (MODE == 0) {
          v += bias1[n] + bias2[n];
          ((_Float16*)Cout)[(size_t)m * N + n] = (_Float16)v;
        } else {
          if (n < nout) ((float*)Cout)[(size_t)m * nout + n] = v + bias1[n];
        }
      }
    }
  }
}

// ---------------------------------------------------------------------------
// Persistent BiLSTM recurrence, R8.
// 128 blocks x 256 thr (4 waves), 1 block/CU. blk<64 fwd else bwd (R5-proven
// static mapping). Block owns 16 units j0..j0+15 = 64 W_hh rows. Wave wv
// owns units 4wv+rr (rr = lane>>4); lane computes the 4 GATE dots of its
// unit over k-slice kq*64..+63 (kq = lane&15).
// hc: [buf][dir][512] u64; word w = [h2(h[2w],h[2w+1]) | tag32],
// tag = (epoch<<12) + gen. Consumer of step t polls buf t&1 for tag SB+t
// (thread polls words 2tid, 2tid+1, depth-2 pipelined); producer stores
// tag SB+t+1 into buf (t+1)&1. 2-buffer safety: reaching t+2 data-depends
// on having polled gen t+1, so gen t can't be overwritten early.
// ---------------------------------------------------------------------------
__global__ __launch_bounds__(256, 1) void lstm_rec(
    const float* __restrict__ Whh_f, const float* __restrict__ Whh_b,
    const _Float16* __restrict__ xp,   // [2][2048][4096]
    u64* __restrict__ hc,              // [2][2][512] agent-scope
    unsigned* __restrict__ ep,         // epoch counter (post-incremented)
    _Float16* __restrict__ hhist) {    // [2048][2048]
  const int tid = threadIdx.x;
  const int blk = blockIdx.x;
  const int dir = blk >> 6;
  const int ib = blk & 63;
  const int j0 = ib * 16;
  const int wv = tid >> 6;
  const int l = tid & 63;
  const int rr = l >> 4;     // unit replica 0..3 (DPP row)
  const int kq = l & 15;     // 16 k-slices of 64
  const int wrow_u = j0 + 4 * wv + rr;  // unit index within [0,1024)

  const unsigned SB =
      (__hip_atomic_load(ep, __ATOMIC_RELAXED, __HIP_MEMORY_SCOPE_AGENT) - 1u) << 12;

  const float* Whh = dir ? Whh_b : Whh_f;
  const _Float16* xpd = xp + (size_t)dir * (2048u * 4096u);

  __shared__ unsigned int lds_h[2][16 * 36];  // [buf][seg stride 36]

  // one-time: W_hh[g*1024 + wrow_u][kq*64 .. +63] -> f16 regs, g = gate 0..3
  unsigned int w[4][32];
#pragma unroll
  for (int g = 0; g < 4; ++g) {
    const float* wp = Whh + (size_t)(g * 1024 + wrow_u) * 1024 + kq * 64;
#pragma unroll
    for (int i = 0; i < 16; ++i) {
      float4 v = ((const float4*)wp)[i];
      w[g][2 * i] = packh2(v.x, v.y);
      w[g][2 * i + 1] = packh2(v.z, v.w);
    }
  }

  float c = 0.f;  // cell state for unit wrow_u (replicated across 16 lanes)

  // x_proj for t=0: 4 gate preacts of unit wrow_u (stride-1024 scalars)
  float xf0, xf1, xf2, xf3;
  {
    const _Float16* xr = xpd + wrow_u;
    xf0 = (float)xr[0]; xf1 = (float)xr[1024];
    xf2 = (float)xr[2048]; xf3 = (float)xr[3072];
  }

  for (int t = 0; t < T_LEN; ++t) {
    const int buf = t & 1;
    const unsigned exp0 = SB + (unsigned)t;
    // ---- depth-2 pipelined poll of own 2 words (2tid, 2tid+1) ----
    unsigned d0, d1;
    {
      const u64* src = hc + (((size_t)buf * 2 + dir) * 512 + 2 * tid);
      u64 a0 = aload(&src[0]), a1 = aload(&src[1]);   // batch A in flight
      u64 b0 = aload(&src[0]), b1 = aload(&src[1]);   // batch B in flight
      int cnt = 0;
      for (;;) {
        // check A (waits A only; B stays outstanding)
        if (((unsigned)a0 == exp0) & ((unsigned)a1 == exp0)) {
          d0 = (unsigned)(a0 >> 32); d1 = (unsigned)(a1 >> 32); break;
        }
        a0 = aload(&src[0]); a1 = aload(&src[1]);     // reissue A behind B
        if (((unsigned)b0 == exp0) & ((unsigned)b1 == exp0)) {
          d0 = (unsigned)(b0 >> 32); d1 = (unsigned)(b1 >> 32); break;
        }
        b0 = aload(&src[0]); b1 = aload(&src[1]);     // reissue B behind A
        if (++cnt > (1 << 12)) {                      // bailout: never hang
          d0 = (unsigned)(a0 >> 32); d1 = (unsigned)(a1 >> 32); break;
        }
      }
    }

    // prefetch NEXT step's x_proj (4 gate scalars; off the critical path)
    int tnx = (t + 1 < T_LEN) ? t + 1 : t;
    const _Float16* xr = xpd + (size_t)tnx * 4096 + wrow_u;
    _Float16 n0 = xr[0], n1 = xr[1024], n2 = xr[2048], n3 = xr[3072];

    // stage h payload: dwords 2tid,2tid+1 -> seg tid>>4, offset 2*(tid&15)
    *(uint2*)&lds_h[buf][(tid >> 4) * 36 + 2 * (tid & 15)] = make_uint2(d0, d1);
    __syncthreads();  // single barrier per step (double-buffered LDS)

    // ---- dot: 4 gates x 64-elem slice; 8 ds_read_b128, 128 fdot2 ----
    float acc0 = 0.f, acc1 = 0.f, acc2 = 0.f, acc3 = 0.f;
    const uint4* hp = (const uint4*)&lds_h[buf][kq * 36];
#pragma unroll
    for (int i = 0; i < 8; ++i) {
      uint4 hv = hp[i];
      acc0 = fdot2u(w[0][4 * i + 0], hv.x, acc0);
      acc0 = fdot2u(w[0][4 * i + 1], hv.y, acc0);
      acc0 = fdot2u(w[0][4 * i + 2], hv.z, acc0);
      acc0 = fdot2u(w[0][4 * i + 3], hv.w, acc0);
      acc1 = fdot2u(w[1][4 * i + 0], hv.x, acc1);
      acc1 = fdot2u(w[1][4 * i + 1], hv.y, acc1);
      acc1 = fdot2u(w[1][4 * i + 2], hv.z, acc1);
      acc1 = fdot2u(w[1][4 * i + 3], hv.w, acc1);
      acc2 = fdot2u(w[2][4 * i + 0], hv.x, acc2);
      acc2 = fdot2u(w[2][4 * i + 1], hv.y, acc2);
      acc2 = fdot2u(w[2][4 * i + 2], hv.z, acc2);
      acc2 = fdot2u(w[2][4 * i + 3], hv.w, acc2);
      acc3 = fdot2u(w[3][4 * i + 0], hv.x, acc3);
      acc3 = fdot2u(w[3][4 * i + 1], hv.y, acc3);
      acc3 = fdot2u(w[3][4 * i + 2], hv.z, acc3);
      acc3 = fdot2u(w[3][4 * i + 3], hv.w, acc3);
    }
    // 16-lane reduce via DPP (VALU-only): xor1, xor2, 8-mirror, 16-mirror
    DPP_ROUND(0xB1);   // quad_perm {1,0,3,2}
    DPP_ROUND(0x4E);   // quad_perm {2,3,0,1}
    DPP_ROUND(0x141);  // row_half_mirror
    DPP_ROUND(0x140);  // row_mirror

    // lane now holds all 4 gate preacts of unit wrow_u directly
    float ii = sigmoidf_(acc0 + xf0);
    float ff = sigmoidf_(acc1 + xf1);
    float g_ = tanhf_(acc2 + xf2);
    float oo = sigmoidf_(acc3 + xf3);
    c = ff * c + ii * g_;
    float h = oo * tanhf_(c);  // replicated over 16 lanes of row rr

    // publish: pair rows (0,1) and (2,3), then fold rows 2->0; lane0 stores
    float hx = __shfl_xor(h, 16, 64);   // row0 gets h1, row2 gets h3
    unsigned pk = packh2(h, hx);        // row0: (h0,h1)  row2: (h2,h3)
    unsigned pko = (unsigned)__shfl_xor((int)pk, 32, 64);  // row0 gets (h2,h3)
    if (l == 0) {
      unsigned tg = SB + (unsigned)(t + 1);
      u64 w0 = ((u64)pk << 32) | tg;
      u64 w1 = ((u64)pko << 32) | tg;
      u64* dst = hc + (((size_t)((t + 1) & 1) * 2 + dir) * 512 +
                       (size_t)(ib * 8 + 2 * wv));
      __hip_atomic_store(&dst[0], w0, __ATOMIC_RELAXED, __HIP_MEMORY_SCOPE_AGENT);
      __hip_atomic_store(&dst[1], w1, __ATOMIC_RELAXED, __HIP_MEMORY_SCOPE_AGENT);
      // hhist AFTER publish: off the critical sync path
      int tout = dir ? (T_LEN - 1 - t) : t;
      *(uint2*)&hhist[(size_t)tout * 2048 + (size_t)(dir * 1024 + j0 + 4 * wv)] =
          make_uint2(pk, pko);
    }

    // convert next-step xp (prefetched above)
    xf0 = (float)n0; xf1 = (float)n1; xf2 = (float)n2; xf3 = (float)n3;
  }
}

// ---------------------------------------------------------------------------
extern "C" void kernel_launch(void* const* d_in, const int* in_sizes, int n_in,
                              void* d_out, int out_size, void* d_ws, size_t ws_size,
                              hipStream_t stream) {
  (void)in_sizes; (void)n_in; (void)out_size; (void)ws_size;
  const float* x     = (const float*)d_in[0];
  const float* Wih_f = (const float*)d_in[1];
  const float* Whh_f = (const float*)d_in[2];
  const float* bih_f = (const float*)d_in[3];
  const float* bhh_f = (const float*)d_in[4];
  const float* Wih_b = (const float*)d_in[5];
  const float* Whh_b = (const float*)d_in[6];
  const float* bih_b = (const float*)d_in[7];
  const float* bhh_b = (const float*)d_in[8];
  const float* fcW   = (const float*)d_in[9];
  const float* fcb   = (const float*)d_in[10];

  char* ws = (char*)d_ws;
  _Float16* xf16   = (_Float16*)(ws + 0);
  _Float16* wih16f = (_Float16*)(ws + 4194304);
  _Float16* wih16b = (_Float16*)(ws + 12582912);
  _Float16* fcw16  = (_Float16*)(ws + 20971520);
  _Float16* xp16   = (_Float16*)(ws + 25165824);   // [2][2048][4096]
  _Float16* hhist  = (_Float16*)(ws + 58720256);   // [2048][2048]
  u64*      hc     = (u64*)     (ws + 67108864);   // [2][2][512]
  unsigned* epoch  = (unsigned*)(ws + 67141632);   // epoch counter

  const size_t SX = 2097152, SW = 4194304, SFC = 2097152;
  const size_t total_cvt = SX + 2 * SW + SFC;

  convert_all<<<dim3((unsigned)((total_cvt + 255) / 256)), 256, 0, stream>>>(
      x, Wih_f, Wih_b, fcW, xf16, wih16f, wih16b, fcw16);
  init_state<<<1, 256, 0, stream>>>(hc, epoch);

  gemm_f16<0><<<dim3(512), 256, 0, stream>>>(xf16, wih16f, bih_f, bhh_f,
                                             (void*)xp16, 2048, 4096, 1024, 4096, 0);
  gemm_f16<0><<<dim3(512), 256, 0, stream>>>(xf16, wih16b, bih_b, bhh_b,
                                             (void*)(xp16 + (size_t)2048 * 4096),
                                             2048, 4096, 1024, 4096, 1);

  lstm_rec<<<dim3(128), 256, 0, stream>>>(Whh_f, Whh_b, xp16, hc, epoch, hhist);

  gemm_f16<1><<<dim3(128), 256, 0, stream>>>(hhist, fcw16, fcb, nullptr,
                                             d_out, 2048, 1024, 2048, 1000, 0);
}

// Round 4
// 4157.437 us; speedup vs baseline: 1.7255x; 1.7255x over previous
//
#include <hip/hip_runtime.h>
#include <hip/hip_bf16.h>
#include <cstdint>

// ---------------------------------------------------------------------------
// BiLSTM: x[2048,1024] -> bidirectional LSTM (H=1024) -> FC to 1000 classes.
//   1. convert_all: fp32 -> f16 copies of x, W_ih_f, W_ih_b, fc_W
//   2. gemm_f16<0>: x_proj_d = x_d @ W_ih_d^T + b_ih + b_hh   (f16 MFMA)
//   3. lstm_rec R9: R5-proven agent-scope handshake + single-invalidation
//      publish. Model (R5..R8 evidence): polls spin in local L2; an agent
//      atomic store write-throughs to IC and invalidates remote L2 copies;
//      consumers re-fetch once per invalidation. R5 had each 64B hc line
//      written by 4 waves at staggered times -> up to 4 invalidation/fetch
//      rounds per line per step. R9: waves publish {tag|pay} u64s to LDS
//      staging; wave0 lanes 0-7 poll staging then issue all 8 agent stores
//      of the block's line in ONE wave instruction -> ~one invalidation.
//      Consumer poll = exact R5 (single-issue; R8's depth-2 reverted: it
//      doubled IC pressure and 2.2x'd the kernel). xp prefetch issues
//      BEFORE the poll so the barrier's vmcnt(0) never waits on it.
//      Kept from R7/R8 (verified): gates-per-lane layout + DPP reduce.
//   4. gemm_f16<1>: out = h_hist @ fc_W^T + fc_b
// ---------------------------------------------------------------------------

typedef __fp16 h2 __attribute__((ext_vector_type(2)));
typedef __fp16 h8 __attribute__((ext_vector_type(8)));
typedef float f4 __attribute__((ext_vector_type(4)));
typedef unsigned long long u64;

#define T_LEN 2048

static __device__ __forceinline__ unsigned int packh2(float a, float b) {
  h2 r = __builtin_amdgcn_cvt_pkrtz(a, b);
  return __builtin_bit_cast(unsigned int, r);
}
static __device__ __forceinline__ float fdot2u(unsigned int a, unsigned int b, float c) {
  return __builtin_amdgcn_fdot2(__builtin_bit_cast(h2, a), __builtin_bit_cast(h2, b), c, false);
}
static __device__ __forceinline__ float sigmoidf_(float x) {
  return 1.f / (1.f + __expf(-x));
}
static __device__ __forceinline__ float tanhf_(float x) {
  float e = __expf(-2.f * fabsf(x));
  float r = (1.f - e) / (1.f + e);
  return copysignf(r, x);
}
static __device__ __forceinline__ u64 aload(const u64* p) {
  return __hip_atomic_load(p, __ATOMIC_RELAXED, __HIP_MEMORY_SCOPE_AGENT);
}

// 16-lane (DPP-row) sum reduction: xor1, xor2 (quad_perm), row_half_mirror,
// row_mirror. All 16 lanes of the row end with the row sum. (R7/R8-verified.)
#define DPP_ADD1(v, CTRL)                                                      \
  v += __builtin_bit_cast(                                                     \
      float, __builtin_amdgcn_update_dpp(0, __builtin_bit_cast(int, v), CTRL,  \
                                         0xf, 0xf, true))
#define DPP_ROUND(CTRL)                                                        \
  DPP_ADD1(acc0, CTRL);                                                        \
  DPP_ADD1(acc1, CTRL);                                                        \
  DPP_ADD1(acc2, CTRL);                                                        \
  DPP_ADD1(acc3, CTRL)

// ---------------------------------------------------------------------------
__global__ void convert_all(const float* __restrict__ x, const float* __restrict__ wf,
                            const float* __restrict__ wb, const float* __restrict__ fcw,
                            _Float16* __restrict__ xf, _Float16* __restrict__ wff,
                            _Float16* __restrict__ wbf, _Float16* __restrict__ fcwf) {
  const size_t SX = 2097152, SW = 4194304, SFC = 2097152;
  size_t i = (size_t)blockIdx.x * 256 + threadIdx.x;
  if (i < SX) {
    xf[i] = (_Float16)x[i];
  } else if (i < SX + SW) {
    size_t j = i - SX; wff[j] = (_Float16)wf[j];
  } else if (i < SX + 2 * SW) {
    size_t j = i - SX - SW; wbf[j] = (_Float16)wb[j];
  } else if (i < SX + 2 * SW + SFC) {
    size_t j = i - SX - 2 * SW;
    int row = (int)(j >> 11), col = (int)(j & 2047);
    fcwf[j] = (row < 1000) ? (_Float16)fcw[(size_t)row * 2048 + col] : (_Float16)0.f;
  }
}

// epoch bump + seed gen-0 tags (payload h=0, tag=epoch<<12).
__global__ void init_state(u64* __restrict__ hc, unsigned* __restrict__ ep) {
  __shared__ unsigned sbs;
  if (threadIdx.x == 0) sbs = atomicAdd(ep, 1u) << 12;
  __syncthreads();
  u64 v = (u64)sbs;
  for (int i = threadIdx.x; i < 2048; i += 256)
    __hip_atomic_store(&hc[i], v, __ATOMIC_RELAXED, __HIP_MEMORY_SCOPE_AGENT);
}

// ---------------------------------------------------------------------------
// f16 GEMM, 128x128 tile, BK=64 (unchanged — verified R2/R3/R4)
// ---------------------------------------------------------------------------
#define LSTR 80

template <int MODE>
__global__ __launch_bounds__(256, 2) void gemm_f16(
    const _Float16* __restrict__ A, const _Float16* __restrict__ B,
    const float* __restrict__ bias1, const float* __restrict__ bias2,
    void* __restrict__ Cout, int M, int N, int K, int nout, int rev) {
  __shared__ _Float16 As[128 * LSTR];
  __shared__ _Float16 Bs[128 * LSTR];

  const int tid = threadIdx.x;
  const int ntn = N >> 7;
  const int tm = blockIdx.x / ntn, tn = blockIdx.x % ntn;
  const int wid = tid >> 6, lane = tid & 63;
  const int wr = wid >> 1, wc = wid & 1;
  const int quad = lane >> 4, l16 = lane & 15;

  const int srow = tid >> 1, seg = tid & 1;
  const int arow = rev ? (M - 1 - (tm * 128 + srow)) : (tm * 128 + srow);
  const int brow = tn * 128 + srow;

  f4 acc[4][4];
#pragma unroll
  for (int i = 0; i < 4; ++i)
#pragma unroll
    for (int j = 0; j < 4; ++j) acc[i][j] = (f4)0.f;

  for (int k0 = 0; k0 < K; k0 += 64) {
    uint4 va[4], vb[4];
    const uint4* gpa = (const uint4*)(A + (size_t)arow * K + k0 + seg * 32);
    const uint4* gpb = (const uint4*)(B + (size_t)brow * K + k0 + seg * 32);
#pragma unroll
    for (int c = 0; c < 4; ++c) va[c] = gpa[c];
#pragma unroll
    for (int c = 0; c < 4; ++c) vb[c] = gpb[c];

    __syncthreads();
    uint4* lpa = (uint4*)&As[srow * LSTR + seg * 32];
    uint4* lpb = (uint4*)&Bs[srow * LSTR + seg * 32];
#pragma unroll
    for (int c = 0; c < 4; ++c) lpa[c] = va[c];
#pragma unroll
    for (int c = 0; c < 4; ++c) lpb[c] = vb[c];
    __syncthreads();

#pragma unroll
    for (int kk = 0; kk < 64; kk += 32) {
      h8 af[4], bf[4];
#pragma unroll
      for (int i = 0; i < 4; ++i) {
        int m = wr * 64 + i * 16 + l16;
        af[i] = *(const h8*)&As[m * LSTR + kk + quad * 8];
        int n = wc * 64 + i * 16 + l16;
        bf[i] = *(const h8*)&Bs[n * LSTR + kk + quad * 8];
      }
#pragma unroll
      for (int i = 0; i < 4; ++i)
#pragma unroll
        for (int j = 0; j < 4; ++j)
          acc[i][j] = __builtin_amdgcn_mfma_f32_16x16x32_f16(af[i], bf[j], acc[i][j], 0, 0, 0);
    }
  }

  const int cm0 = tm * 128 + wr * 64, cn0 = tn * 128 + wc * 64;
#pragma unroll
  for (int i = 0; i < 4; ++i) {
#pragma unroll
    for (int j = 0; j < 4; ++j) {
      int n = cn0 + j * 16 + l16;
#pragma unroll
      for (int r = 0; r < 4; ++r) {
        int m = cm0 + i * 16 + quad * 4 + r;
        float v = acc[i][j][r];
        if (MODE == 0) {
          v += bias1[n] + bias2[n];
          ((_Float16*)Cout)[(size_t)m * N + n] = (_Float16)v;
        } else {
          if (n < nout) ((float*)Cout)[(size_t)m * nout + n] = v + bias1[n];
        }
      }
    }
  }
}

// ---------------------------------------------------------------------------
// Persistent BiLSTM recurrence, R9.
// 128 blocks x 256 thr (4 waves), 1 block/CU. blk<64 fwd else bwd. Block
// owns 16 units j0..j0+15 = 64 W_hh rows = ONE 64B hc line (8 u64 words).
// Wave wv owns units 4wv+rr (rr=lane>>4); lane computes the 4 GATE dots of
// its unit over k-slice kq*64..+63 (kq=lane&15). DPP 16-lane reduce.
// hc: [buf][dir][512] u64; word w = [h2(h[2w],h[2w+1]) | tag32],
// tag = (epoch<<12)+gen. Publish: per-wave lane0 -> LDS staging (2 u64 with
// embedded tags); wave0 lanes 0-7 poll staging then store the whole line
// with ONE wave instruction (8 agent u64 stores, same 64B line) -> single
// invalidation event; consumers fetch the line once. Consumer poll: exact
// R5 single-issue loop. 2-buffer safety as R5 (reaching t+2 data-depends on
// having consumed t+1).
// ---------------------------------------------------------------------------
__global__ __launch_bounds__(256, 1) void lstm_rec(
    const float* __restrict__ Whh_f, const float* __restrict__ Whh_b,
    const _Float16* __restrict__ xp,   // [2][2048][4096]
    u64* __restrict__ hc,              // [2][2][512] agent-scope
    unsigned* __restrict__ ep,         // epoch counter (post-incremented)
    _Float16* __restrict__ hhist) {    // [2048][2048]
  const int tid = threadIdx.x;
  const int blk = blockIdx.x;
  const int dir = blk >> 6;
  const int ib = blk & 63;
  const int j0 = ib * 16;
  const int wv = tid >> 6;
  const int l = tid & 63;
  const int rr = l >> 4;     // unit replica 0..3 (DPP row)
  const int kq = l & 15;     // 16 k-slices of 64
  const int wrow_u = j0 + 4 * wv + rr;  // unit index within [0,1024)

  const unsigned SB =
      (__hip_atomic_load(ep, __ATOMIC_RELAXED, __HIP_MEMORY_SCOPE_AGENT) - 1u) << 12;

  const float* Whh = dir ? Whh_b : Whh_f;
  const _Float16* xpd = xp + (size_t)dir * (2048u * 4096u);

  __shared__ unsigned int lds_h[2][16 * 36];  // [buf][seg stride 36]
  __shared__ u64 lds_pub[2][8];               // publish staging, [slot][word]

  // one-time: W_hh[g*1024 + wrow_u][kq*64 .. +63] -> f16 regs, g = gate 0..3
  unsigned int w[4][32];
#pragma unroll
  for (int g = 0; g < 4; ++g) {
    const float* wp = Whh + (size_t)(g * 1024 + wrow_u) * 1024 + kq * 64;
#pragma unroll
    for (int i = 0; i < 16; ++i) {
      float4 v = ((const float4*)wp)[i];
      w[g][2 * i] = packh2(v.x, v.y);
      w[g][2 * i + 1] = packh2(v.z, v.w);
    }
  }

  float c = 0.f;  // cell state for unit wrow_u (replicated across 16 lanes)

  // x_proj for t=0: 4 gate preacts of unit wrow_u (stride-1024 scalars)
  float xf0, xf1, xf2, xf3;
  {
    const _Float16* xr = xpd + wrow_u;
    xf0 = (float)xr[0]; xf1 = (float)xr[1024];
    xf2 = (float)xr[2048]; xf3 = (float)xr[3072];
  }

  for (int t = 0; t < T_LEN; ++t) {
    const int buf = t & 1;
    const unsigned exp0 = SB + (unsigned)t;

    // prefetch NEXT step's x_proj BEFORE the poll: completes under the
    // detection wait, so the barrier's vmcnt(0) never stalls on it.
    int tnx = (t + 1 < T_LEN) ? t + 1 : t;
    const _Float16* xr = xpd + (size_t)tnx * 4096 + wrow_u;
    _Float16 n0 = xr[0], n1 = xr[1024], n2 = xr[2048], n3 = xr[3072];

    // ---- poll own 2 words (2tid, 2tid+1): exact R5 single-issue loop ----
    unsigned d0, d1;
    {
      const u64* src = hc + (((size_t)buf * 2 + dir) * 512 + 2 * tid);
      u64 a = aload(&src[0]);
      u64 b = aload(&src[1]);
      int cnt = 0;
      while ((unsigned)a != exp0 || (unsigned)b != exp0) {
        if (++cnt > (1 << 12)) break;  // bailout: fail absmax, never hang
        a = aload(&src[0]);
        b = aload(&src[1]);
      }
      d0 = (unsigned)(a >> 32);
      d1 = (unsigned)(b >> 32);
    }

    // stage h payload: dwords 2tid,2tid+1 -> seg tid>>4, offset 2*(tid&15)
    *(uint2*)&lds_h[buf][(tid >> 4) * 36 + 2 * (tid & 15)] = make_uint2(d0, d1);
    __syncthreads();  // single barrier per step (double-buffered LDS)

    // ---- dot: 4 gates x 64-elem slice; 8 ds_read_b128, 128 fdot2 ----
    float acc0 = 0.f, acc1 = 0.f, acc2 = 0.f, acc3 = 0.f;
    const uint4* hp = (const uint4*)&lds_h[buf][kq * 36];
#pragma unroll
    for (int i = 0; i < 8; ++i) {
      uint4 hv = hp[i];
      acc0 = fdot2u(w[0][4 * i + 0], hv.x, acc0);
      acc0 = fdot2u(w[0][4 * i + 1], hv.y, acc0);
      acc0 = fdot2u(w[0][4 * i + 2], hv.z, acc0);
      acc0 = fdot2u(w[0][4 * i + 3], hv.w, acc0);
      acc1 = fdot2u(w[1][4 * i + 0], hv.x, acc1);
      acc1 = fdot2u(w[1][4 * i + 1], hv.y, acc1);
      acc1 = fdot2u(w[1][4 * i + 2], hv.z, acc1);
      acc1 = fdot2u(w[1][4 * i + 3], hv.w, acc1);
      acc2 = fdot2u(w[2][4 * i + 0], hv.x, acc2);
      acc2 = fdot2u(w[2][4 * i + 1], hv.y, acc2);
      acc2 = fdot2u(w[2][4 * i + 2], hv.z, acc2);
      acc2 = fdot2u(w[2][4 * i + 3], hv.w, acc2);
      acc3 = fdot2u(w[3][4 * i + 0], hv.x, acc3);
      acc3 = fdot2u(w[3][4 * i + 1], hv.y, acc3);
      acc3 = fdot2u(w[3][4 * i + 2], hv.z, acc3);
      acc3 = fdot2u(w[3][4 * i + 3], hv.w, acc3);
    }
    // 16-lane reduce via DPP (VALU-only): xor1, xor2, 8-mirror, 16-mirror
    DPP_ROUND(0xB1);   // quad_perm {1,0,3,2}
    DPP_ROUND(0x4E);   // quad_perm {2,3,0,1}
    DPP_ROUND(0x141);  // row_half_mirror
    DPP_ROUND(0x140);  // row_mirror

    // lane now holds all 4 gate preacts of unit wrow_u directly
    float ii = sigmoidf_(acc0 + xf0);
    float ff = sigmoidf_(acc1 + xf1);
    float g_ = tanhf_(acc2 + xf2);
    float oo = sigmoidf_(acc3 + xf3);
    c = ff * c + ii * g_;
    float h = oo * tanhf_(c);  // replicated over 16 lanes of row rr

    // pack pairs: rows (0,1) and (2,3), then fold rows 2->0 into lane0
    float hx = __shfl_xor(h, 16, 64);   // row0 gets h1, row2 gets h3
    unsigned pk = packh2(h, hx);        // row0: (h0,h1)  row2: (h2,h3)
    unsigned pko = (unsigned)__shfl_xor((int)pk, 32, 64);  // row0 gets (h2,h3)

    const unsigned tg = SB + (unsigned)(t + 1);
    const int slot = (t + 1) & 1;
    // per-wave lane0 publishes its 2 words into LDS staging (tag embedded)
    if (l == 0) {
      __hip_atomic_store(&lds_pub[slot][2 * wv], ((u64)pk << 32) | tg,
                         __ATOMIC_RELAXED, __HIP_MEMORY_SCOPE_WORKGROUP);
      __hip_atomic_store(&lds_pub[slot][2 * wv + 1], ((u64)pko << 32) | tg,
                         __ATOMIC_RELAXED, __HIP_MEMORY_SCOPE_WORKGROUP);
    }
    // wave0 lanes 0-7: gather the block's full 64B line, store it with ONE
    // wave instruction (8 agent u64 stores to one line -> ~1 invalidation)
    if (tid < 8) {
      u64 v;
      int cc = 0;
      do {
        v = __hip_atomic_load(&lds_pub[slot][tid], __ATOMIC_RELAXED,
                              __HIP_MEMORY_SCOPE_WORKGROUP);
      } while ((unsigned)v != tg && ++cc < (1 << 12));
      u64* dst = hc + (((size_t)slot * 2 + dir) * 512 + (size_t)(ib * 8 + tid));
      __hip_atomic_store(dst, v, __ATOMIC_RELAXED, __HIP_MEMORY_SCOPE_AGENT);
      // hhist AFTER publish (off the critical sync path), 32B coalesced
      int tout = dir ? (T_LEN - 1 - t) : t;
      *(unsigned*)&hhist[(size_t)tout * 2048 + (size_t)(dir * 1024 + j0 + 2 * tid)] =
          (unsigned)(v >> 32);
    }

    // convert next-step xp (prefetched above)
    xf0 = (float)n0; xf1 = (float)n1; xf2 = (float)n2; xf3 = (float)n3;
  }
}

// ---------------------------------------------------------------------------
extern "C" void kernel_launch(void* const* d_in, const int* in_sizes, int n_in,
                              void* d_out, int out_size, void* d_ws, size_t ws_size,
                              hipStream_t stream) {
  (void)in_sizes; (void)n_in; (void)out_size; (void)ws_size;
  const float* x     = (const float*)d_in[0];
  const float* Wih_f = (const float*)d_in[1];
  const float* Whh_f = (const float*)d_in[2];
  const float* bih_f = (const float*)d_in[3];
  const float* bhh_f = (const float*)d_in[4];
  const float* Wih_b = (const float*)d_in[5];
  const float* Whh_b = (const float*)d_in[6];
  const float* bih_b = (const float*)d_in[7];
  const float* bhh_b = (const float*)d_in[8];
  const float* fcW   = (const float*)d_in[9];
  const float* fcb   = (const float*)d_in[10];

  char* ws = (char*)d_ws;
  _Float16* xf16   = (_Float16*)(ws + 0);
  _Float16* wih16f = (_Float16*)(ws + 4194304);
  _Float16* wih16b = (_Float16*)(ws + 12582912);
  _Float16* fcw16  = (_Float16*)(ws + 20971520);
  _Float16* xp16   = (_Float16*)(ws + 25165824);   // [2][2048][4096]
  _Float16* hhist  = (_Float16*)(ws + 58720256);   // [2048][2048]
  u64*      hc     = (u64*)     (ws + 67108864);   // [2][2][512]
  unsigned* epoch  = (unsigned*)(ws + 67141632);   // epoch counter

  const size_t SX = 2097152, SW = 4194304, SFC = 2097152;
  const size_t total_cvt = SX + 2 * SW + SFC;

  convert_all<<<dim3((unsigned)((total_cvt + 255) / 256)), 256, 0, stream>>>(
      x, Wih_f, Wih_b, fcW, xf16, wih16f, wih16b, fcw16);
  init_state<<<1, 256, 0, stream>>>(hc, epoch);

  gemm_f16<0><<<dim3(512), 256, 0, stream>>>(xf16, wih16f, bih_f, bhh_f,
                                             (void*)xp16, 2048, 4096, 1024, 4096, 0);
  gemm_f16<0><<<dim3(512), 256, 0, stream>>>(xf16, wih16b, bih_b, bhh_b,
                                             (void*)(xp16 + (size_t)2048 * 4096),
                                             2048, 4096, 1024, 4096, 1);

  lstm_rec<<<dim3(128), 256, 0, stream>>>(Whh_f, Whh_b, xp16, hc, epoch, hhist);

  gemm_f16<1><<<dim3(128), 256, 0, stream>>>(hhist, fcw16, fcb, nullptr,
                                             d_out, 2048, 1024, 2048, 1000, 0);
}

// Round 5
// 3337.060 us; speedup vs baseline: 2.1497x; 1.2458x over previous
//
#include <hip/hip_runtime.h>
#include <hip/hip_bf16.h>
#include <cstdint>

// ---------------------------------------------------------------------------
// BiLSTM: x[2048,1024] -> bidirectional LSTM (H=1024) -> FC to 1000 classes.
//   1. convert_all: fp32 -> f16 copies of x, W_ih_f, W_ih_b, fc_W
//   2. gemm_f16<0>: x_proj_d = x_d @ W_ih_d^T + b_ih + b_hh   (f16 MFMA)
//   3. lstm_rec R10: R5 handshake skeleton, publish via atomic EXCHANGE.
//      Evidence R5..R9: agent atomic *stores* write through to HBM (R5
//      WRITE 74MB = 4 events/line/step x 64B; R9 aggregated -> 25MB) and
//      cost the chain ~2 HBM-class trips/step. R9's LDS-staged aggregation
//      saved write traffic but its serial hop cost +300ns/step -> reverted.
//      R10: per-wave single-instruction publish (lanes 0-1 each exchange
//      one u64; gates-per-lane layout already replicates both packed words
//      across lanes 0-15, so zero extra shuffles). atomicExch executes at
//      the coherence point and should leave the line cache-dirty (no HBM
//      write-through) -> consumer refetch at cache latency. Falsifier:
//      WRITE_SIZE ~9MB if right, >=17MB if wrong.
//      Ordering fix: poll loads issue FIRST, xp prefetch second, then the
//      check loop -> first check waits vmcnt(4) (polls only) and xp drains
//      under the detection wait (R5 exposed xp at the barrier's vmcnt(0);
//      R9 exposed it in the first poll check).
//      Kept (verified): gates-per-lane + DPP 16-lane reduce, single
//      barrier/step, epoch-salted tags, bailout.
//   4. gemm_f16<1>: out = h_hist @ fc_W^T + fc_b
// ---------------------------------------------------------------------------

typedef __fp16 h2 __attribute__((ext_vector_type(2)));
typedef __fp16 h8 __attribute__((ext_vector_type(8)));
typedef float f4 __attribute__((ext_vector_type(4)));
typedef unsigned long long u64;

#define T_LEN 2048

static __device__ __forceinline__ unsigned int packh2(float a, float b) {
  h2 r = __builtin_amdgcn_cvt_pkrtz(a, b);
  return __builtin_bit_cast(unsigned int, r);
}
static __device__ __forceinline__ float fdot2u(unsigned int a, unsigned int b, float c) {
  return __builtin_amdgcn_fdot2(__builtin_bit_cast(h2, a), __builtin_bit_cast(h2, b), c, false);
}
static __device__ __forceinline__ float sigmoidf_(float x) {
  return 1.f / (1.f + __expf(-x));
}
static __device__ __forceinline__ float tanhf_(float x) {
  float e = __expf(-2.f * fabsf(x));
  float r = (1.f - e) / (1.f + e);
  return copysignf(r, x);
}
static __device__ __forceinline__ u64 aload(const u64* p) {
  return __hip_atomic_load(p, __ATOMIC_RELAXED, __HIP_MEMORY_SCOPE_AGENT);
}

// 16-lane (DPP-row) sum reduction: xor1, xor2 (quad_perm), row_half_mirror,
// row_mirror. All 16 lanes of the row end with the row sum. (R7/R9-verified.)
#define DPP_ADD1(v, CTRL)                                                      \
  v += __builtin_bit_cast(                                                     \
      float, __builtin_amdgcn_update_dpp(0, __builtin_bit_cast(int, v), CTRL,  \
                                         0xf, 0xf, true))
#define DPP_ROUND(CTRL)                                                        \
  DPP_ADD1(acc0, CTRL);                                                        \
  DPP_ADD1(acc1, CTRL);                                                        \
  DPP_ADD1(acc2, CTRL);                                                        \
  DPP_ADD1(acc3, CTRL)

// ---------------------------------------------------------------------------
__global__ void convert_all(const float* __restrict__ x, const float* __restrict__ wf,
                            const float* __restrict__ wb, const float* __restrict__ fcw,
                            _Float16* __restrict__ xf, _Float16* __restrict__ wff,
                            _Float16* __restrict__ wbf, _Float16* __restrict__ fcwf) {
  const size_t SX = 2097152, SW = 4194304, SFC = 2097152;
  size_t i = (size_t)blockIdx.x * 256 + threadIdx.x;
  if (i < SX) {
    xf[i] = (_Float16)x[i];
  } else if (i < SX + SW) {
    size_t j = i - SX; wff[j] = (_Float16)wf[j];
  } else if (i < SX + 2 * SW) {
    size_t j = i - SX - SW; wbf[j] = (_Float16)wb[j];
  } else if (i < SX + 2 * SW + SFC) {
    size_t j = i - SX - 2 * SW;
    int row = (int)(j >> 11), col = (int)(j & 2047);
    fcwf[j] = (row < 1000) ? (_Float16)fcw[(size_t)row * 2048 + col] : (_Float16)0.f;
  }
}

// epoch bump + seed gen-0 tags (payload h=0, tag=epoch<<12).
__global__ void init_state(u64* __restrict__ hc, unsigned* __restrict__ ep) {
  __shared__ unsigned sbs;
  if (threadIdx.x == 0) sbs = atomicAdd(ep, 1u) << 12;
  __syncthreads();
  u64 v = (u64)sbs;
  for (int i = threadIdx.x; i < 2048; i += 256)
    __hip_atomic_store(&hc[i], v, __ATOMIC_RELAXED, __HIP_MEMORY_SCOPE_AGENT);
}

// ---------------------------------------------------------------------------
// f16 GEMM, 128x128 tile, BK=64 (unchanged — verified R2/R3/R4)
// ---------------------------------------------------------------------------
#define LSTR 80

template <int MODE>
__global__ __launch_bounds__(256, 2) void gemm_f16(
    const _Float16* __restrict__ A, const _Float16* __restrict__ B,
    const float* __restrict__ bias1, const float* __restrict__ bias2,
    void* __restrict__ Cout, int M, int N, int K, int nout, int rev) {
  __shared__ _Float16 As[128 * LSTR];
  __shared__ _Float16 Bs[128 * LSTR];

  const int tid = threadIdx.x;
  const int ntn = N >> 7;
  const int tm = blockIdx.x / ntn, tn = blockIdx.x % ntn;
  const int wid = tid >> 6, lane = tid & 63;
  const int wr = wid >> 1, wc = wid & 1;
  const int quad = lane >> 4, l16 = lane & 15;

  const int srow = tid >> 1, seg = tid & 1;
  const int arow = rev ? (M - 1 - (tm * 128 + srow)) : (tm * 128 + srow);
  const int brow = tn * 128 + srow;

  f4 acc[4][4];
#pragma unroll
  for (int i = 0; i < 4; ++i)
#pragma unroll
    for (int j = 0; j < 4; ++j) acc[i][j] = (f4)0.f;

  for (int k0 = 0; k0 < K; k0 += 64) {
    uint4 va[4], vb[4];
    const uint4* gpa = (const uint4*)(A + (size_t)arow * K + k0 + seg * 32);
    const uint4* gpb = (const uint4*)(B + (size_t)brow * K + k0 + seg * 32);
#pragma unroll
    for (int c = 0; c < 4; ++c) va[c] = gpa[c];
#pragma unroll
    for (int c = 0; c < 4; ++c) vb[c] = gpb[c];

    __syncthreads();
    uint4* lpa = (uint4*)&As[srow * LSTR + seg * 32];
    uint4* lpb = (uint4*)&Bs[srow * LSTR + seg * 32];
#pragma unroll
    for (int c = 0; c < 4; ++c) lpa[c] = va[c];
#pragma unroll
    for (int c = 0; c < 4; ++c) lpb[c] = vb[c];
    __syncthreads();

#pragma unroll
    for (int kk = 0; kk < 64; kk += 32) {
      h8 af[4], bf[4];
#pragma unroll
      for (int i = 0; i < 4; ++i) {
        int m = wr * 64 + i * 16 + l16;
        af[i] = *(const h8*)&As[m * LSTR + kk + quad * 8];
        int n = wc * 64 + i * 16 + l16;
        bf[i] = *(const h8*)&Bs[n * LSTR + kk + quad * 8];
      }
#pragma unroll
      for (int i = 0; i < 4; ++i)
#pragma unroll
        for (int j = 0; j < 4; ++j)
          acc[i][j] = __builtin_amdgcn_mfma_f32_16x16x32_f16(af[i], bf[j], acc[i][j], 0, 0, 0);
    }
  }

  const int cm0 = tm * 128 + wr * 64, cn0 = tn * 128 + wc * 64;
#pragma unroll
  for (int i = 0; i < 4; ++i) {
#pragma unroll
    for (int j = 0; j < 4; ++j) {
      int n = cn0 + j * 16 + l16;
#pragma unroll
      for (int r = 0; r < 4; ++r) {
        int m = cm0 + i * 16 + quad * 4 + r;
        float v = acc[i][j][r];
        if (MODE == 0) {
          v += bias1[n] + bias2[n];
          ((_Float16*)Cout)[(size_t)m * N + n] = (_Float16)v;
        } else {
          if (n < nout) ((float*)Cout)[(size_t)m * nout + n] = v + bias1[n];
        }
      }
    }
  }
}

// ---------------------------------------------------------------------------
// Persistent BiLSTM recurrence, R10.
// 128 blocks x 256 thr (4 waves), 1 block/CU. blk<64 fwd else bwd. Block
// owns 16 units j0..j0+15 = 64 W_hh rows = one 64B hc line (8 u64 words).
// Wave wv owns units 4wv+rr (rr=lane>>4); lane computes the 4 GATE dots of
// its unit over k-slice kq*64..+63 (kq=lane&15). DPP 16-lane reduce.
// hc: [buf][dir][512] u64; word w = [h2(h[2w],h[2w+1]) | tag32],
// tag = (epoch<<12)+gen. Publish: lanes 0-1 of each wave atomicExch their
// wave's 2 words in ONE instruction (both packed words are replicated
// across lanes 0-15 by construction). Consumer poll: R5 single-issue loop;
// poll loads issue before the xp prefetch so the first check waits only
// the polls. 2-buffer safety as R5.
// ---------------------------------------------------------------------------
__global__ __launch_bounds__(256, 1) void lstm_rec(
    const float* __restrict__ Whh_f, const float* __restrict__ Whh_b,
    const _Float16* __restrict__ xp,   // [2][2048][4096]
    u64* __restrict__ hc,              // [2][2][512] agent-scope
    unsigned* __restrict__ ep,         // epoch counter (post-incremented)
    _Float16* __restrict__ hhist) {    // [2048][2048]
  const int tid = threadIdx.x;
  const int blk = blockIdx.x;
  const int dir = blk >> 6;
  const int ib = blk & 63;
  const int j0 = ib * 16;
  const int wv = tid >> 6;
  const int l = tid & 63;
  const int rr = l >> 4;     // unit replica 0..3 (DPP row)
  const int kq = l & 15;     // 16 k-slices of 64
  const int wrow_u = j0 + 4 * wv + rr;  // unit index within [0,1024)

  const unsigned SB =
      (__hip_atomic_load(ep, __ATOMIC_RELAXED, __HIP_MEMORY_SCOPE_AGENT) - 1u) << 12;

  const float* Whh = dir ? Whh_b : Whh_f;
  const _Float16* xpd = xp + (size_t)dir * (2048u * 4096u);

  __shared__ unsigned int lds_h[2][16 * 36];  // [buf][seg stride 36]

  // one-time: W_hh[g*1024 + wrow_u][kq*64 .. +63] -> f16 regs, g = gate 0..3
  unsigned int w[4][32];
#pragma unroll
  for (int g = 0; g < 4; ++g) {
    const float* wp = Whh + (size_t)(g * 1024 + wrow_u) * 1024 + kq * 64;
#pragma unroll
    for (int i = 0; i < 16; ++i) {
      float4 v = ((const float4*)wp)[i];
      w[g][2 * i] = packh2(v.x, v.y);
      w[g][2 * i + 1] = packh2(v.z, v.w);
    }
  }

  float c = 0.f;  // cell state for unit wrow_u (replicated across 16 lanes)

  // x_proj for t=0: 4 gate preacts of unit wrow_u (stride-1024 scalars)
  float xf0, xf1, xf2, xf3;
  {
    const _Float16* xr = xpd + wrow_u;
    xf0 = (float)xr[0]; xf1 = (float)xr[1024];
    xf2 = (float)xr[2048]; xf3 = (float)xr[3072];
  }

  for (int t = 0; t < T_LEN; ++t) {
    const int buf = t & 1;
    const unsigned exp0 = SB + (unsigned)t;

    // ---- poll own 2 words (2tid, 2tid+1) ----
    // Issue the poll loads FIRST, then the xp prefetch: the first check
    // then needs only vmcnt(4) (polls are oldest in the FIFO) while the 4
    // slow xp loads drain under the detection wait.
    const u64* src = hc + (((size_t)buf * 2 + dir) * 512 + 2 * tid);
    u64 a = aload(&src[0]);
    u64 b = aload(&src[1]);

    int tnx = (t + 1 < T_LEN) ? t + 1 : t;
    const _Float16* xr = xpd + (size_t)tnx * 4096 + wrow_u;
    _Float16 n0 = xr[0], n1 = xr[1024], n2 = xr[2048], n3 = xr[3072];

    unsigned d0, d1;
    {
      int cnt = 0;
      while ((unsigned)a != exp0 || (unsigned)b != exp0) {
        if (++cnt > (1 << 12)) break;  // bailout: fail absmax, never hang
        a = aload(&src[0]);
        b = aload(&src[1]);
      }
      d0 = (unsigned)(a >> 32);
      d1 = (unsigned)(b >> 32);
    }

    // stage h payload: dwords 2tid,2tid+1 -> seg tid>>4, offset 2*(tid&15)
    *(uint2*)&lds_h[buf][(tid >> 4) * 36 + 2 * (tid & 15)] = make_uint2(d0, d1);
    __syncthreads();  // single barrier per step (double-buffered LDS)

    // ---- dot: 4 gates x 64-elem slice; 8 ds_read_b128, 128 fdot2 ----
    float acc0 = 0.f, acc1 = 0.f, acc2 = 0.f, acc3 = 0.f;
    const uint4* hp = (const uint4*)&lds_h[buf][kq * 36];
#pragma unroll
    for (int i = 0; i < 8; ++i) {
      uint4 hv = hp[i];
      acc0 = fdot2u(w[0][4 * i + 0], hv.x, acc0);
      acc0 = fdot2u(w[0][4 * i + 1], hv.y, acc0);
      acc0 = fdot2u(w[0][4 * i + 2], hv.z, acc0);
      acc0 = fdot2u(w[0][4 * i + 3], hv.w, acc0);
      acc1 = fdot2u(w[1][4 * i + 0], hv.x, acc1);
      acc1 = fdot2u(w[1][4 * i + 1], hv.y, acc1);
      acc1 = fdot2u(w[1][4 * i + 2], hv.z, acc1);
      acc1 = fdot2u(w[1][4 * i + 3], hv.w, acc1);
      acc2 = fdot2u(w[2][4 * i + 0], hv.x, acc2);
      acc2 = fdot2u(w[2][4 * i + 1], hv.y, acc2);
      acc2 = fdot2u(w[2][4 * i + 2], hv.z, acc2);
      acc2 = fdot2u(w[2][4 * i + 3], hv.w, acc2);
      acc3 = fdot2u(w[3][4 * i + 0], hv.x, acc3);
      acc3 = fdot2u(w[3][4 * i + 1], hv.y, acc3);
      acc3 = fdot2u(w[3][4 * i + 2], hv.z, acc3);
      acc3 = fdot2u(w[3][4 * i + 3], hv.w, acc3);
    }
    // 16-lane reduce via DPP (VALU-only): xor1, xor2, 8-mirror, 16-mirror
    DPP_ROUND(0xB1);   // quad_perm {1,0,3,2}
    DPP_ROUND(0x4E);   // quad_perm {2,3,0,1}
    DPP_ROUND(0x141);  // row_half_mirror
    DPP_ROUND(0x140);  // row_mirror

    // lane now holds all 4 gate preacts of unit wrow_u directly
    float ii = sigmoidf_(acc0 + xf0);
    float ff = sigmoidf_(acc1 + xf1);
    float g_ = tanhf_(acc2 + xf2);
    float oo = sigmoidf_(acc3 + xf3);
    c = ff * c + ii * g_;
    float h = oo * tanhf_(c);  // replicated over 16 lanes of row rr

    // pack pairs: after these shuffles, ALL lanes 0-15 hold pk=(h0,h1) and
    // pko=(h2,h3) (h replicated across each 16-lane row by construction).
    float hx = __shfl_xor(h, 16, 64);   // rows 0<->1, rows 2<->3
    unsigned pk = packh2(h, hx);        // rows 0-15: (h0,h1); rows 32-47: (h2,h3)
    unsigned pko = (unsigned)__shfl_xor((int)pk, 32, 64);  // rows 0-15: (h2,h3)

    const unsigned tg = SB + (unsigned)(t + 1);
    const int slot = (t + 1) & 1;
    // publish: lanes 0-1 of each wave exchange their wave's 2 words in ONE
    // wave instruction. RMW executes at the coherence point -> line stays
    // cache-dirty (hypothesis; falsifier = WRITE_SIZE).
    if (l < 2) {
      u64 v = (l == 0) ? (((u64)pk << 32) | tg) : (((u64)pko << 32) | tg);
      u64* dst = hc + (((size_t)slot * 2 + dir) * 512 +
                       (size_t)(ib * 8 + 2 * wv + l));
      (void)__hip_atomic_exchange(dst, v, __ATOMIC_RELAXED,
                                  __HIP_MEMORY_SCOPE_AGENT);
      // hhist AFTER publish (off the critical sync path): 2 lanes x 4B
      int tout = dir ? (T_LEN - 1 - t) : t;
      *(unsigned*)&hhist[(size_t)tout * 2048 +
                         (size_t)(dir * 1024 + j0 + 4 * wv + 2 * l)] =
          (l == 0) ? pk : pko;
    }

    // convert next-step xp (prefetched above)
    xf0 = (float)n0; xf1 = (float)n1; xf2 = (float)n2; xf3 = (float)n3;
  }
}

// ---------------------------------------------------------------------------
extern "C" void kernel_launch(void* const* d_in, const int* in_sizes, int n_in,
                              void* d_out, int out_size, void* d_ws, size_t ws_size,
                              hipStream_t stream) {
  (void)in_sizes; (void)n_in; (void)out_size; (void)ws_size;
  const float* x     = (const float*)d_in[0];
  const float* Wih_f = (const float*)d_in[1];
  const float* Whh_f = (const float*)d_in[2];
  const float* bih_f = (const float*)d_in[3];
  const float* bhh_f = (const float*)d_in[4];
  const float* Wih_b = (const float*)d_in[5];
  const float* Whh_b = (const float*)d_in[6];
  const float* bih_b = (const float*)d_in[7];
  const float* bhh_b = (const float*)d_in[8];
  const float* fcW   = (const float*)d_in[9];
  const float* fcb   = (const float*)d_in[10];

  char* ws = (char*)d_ws;
  _Float16* xf16   = (_Float16*)(ws + 0);
  _Float16* wih16f = (_Float16*)(ws + 4194304);
  _Float16* wih16b = (_Float16*)(ws + 12582912);
  _Float16* fcw16  = (_Float16*)(ws + 20971520);
  _Float16* xp16   = (_Float16*)(ws + 25165824);   // [2][2048][4096]
  _Float16* hhist  = (_Float16*)(ws + 58720256);   // [2048][2048]
  u64*      hc     = (u64*)     (ws + 67108864);   // [2][2][512]
  unsigned* epoch  = (unsigned*)(ws + 67141632);   // epoch counter

  const size_t SX = 2097152, SW = 4194304, SFC = 2097152;
  const size_t total_cvt = SX + 2 * SW + SFC;

  convert_all<<<dim3((unsigned)((total_cvt + 255) / 256)), 256, 0, stream>>>(
      x, Wih_f, Wih_b, fcW, xf16, wih16f, wih16b, fcw16);
  init_state<<<1, 256, 0, stream>>>(hc, epoch);

  gemm_f16<0><<<dim3(512), 256, 0, stream>>>(xf16, wih16f, bih_f, bhh_f,
                                             (void*)xp16, 2048, 4096, 1024, 4096, 0);
  gemm_f16<0><<<dim3(512), 256, 0, stream>>>(xf16, wih16b, bih_b, bhh_b,
                                             (void*)(xp16 + (size_t)2048 * 4096),
                                             2048, 4096, 1024, 4096, 1);

  lstm_rec<<<dim3(128), 256, 0, stream>>>(Whh_f, Whh_b, xp16, hc, epoch, hhist);

  gemm_f16<1><<<dim3(128), 256, 0, stream>>>(hhist, fcw16, fcb, nullptr,
                                             d_out, 2048, 1024, 2048, 1000, 0);
}